// Round 1
// baseline (1127.720 us; speedup 1.0000x reference)
//
#include <hip/hip_runtime.h>

// SparseAttention: B=1, S=2048, H=16, D=128, WINDOW=512, RATIO=4.
// kv shared across heads. Per query i: window rows [max(0,i-511), i] from
// kv_states, compressed rows c < (i+1)/4 from kv_compress, plus sink logit.
// Softmax over (window + compressed + sink), output = probs @ kv.

constexpr int kS = 2048;
constexpr int kH = 16;
constexpr int kD = 128;
constexpr int kWin = 512;
constexpr int HG = 8;          // heads per block (kv reused 8x)
constexpr int NT = 256;        // 4 waves
constexpr int MAXN = kWin + kS / 4;  // 1024 max kv rows per query

__global__ __launch_bounds__(NT) void sparse_attn_f32(
    const float* __restrict__ q,    // [S,H,D]
    const float* __restrict__ kvs,  // [S,D]
    const float* __restrict__ sink, // [H]
    const float* __restrict__ kvc,  // [S/4,D]
    float* __restrict__ out)        // [S,H,D]
{
  const int i   = blockIdx.x;
  const int h0  = blockIdx.y * HG;
  const int tid = threadIdx.x;

  const int ws = (i >= kWin) ? (i - kWin + 1) : 0;  // window start
  const int wn = i - ws + 1;                        // window count (<=512)
  const int nc = (i + 1) >> 2;                      // compressed count (<=512)
  const int n  = wn + nc;                           // total kv rows (<=1024)

  __shared__ float  lq[HG][kD];          // scaled q rows       (4 KB)
  __shared__ float  lp[HG][MAXN];        // logits -> probs     (32 KB)
  __shared__ float2 part[4][HG][kD / 2]; // PV partials         (16 KB)
  __shared__ float  dinv[HG];

  const float scale = 0.08838834764831845f;  // 1/sqrt(128)

  // stage scaled q rows for the 8 heads
  for (int idx = tid; idx < HG * kD; idx += NT) {
    const int hh = idx >> 7, d = idx & (kD - 1);
    lq[hh][d] = q[((size_t)i * kH + h0 + hh) * kD + d] * scale;
  }
  __syncthreads();

  // ---- QK^T: each thread owns kv rows jj = tid + k*NT, dots vs 8 heads ----
  for (int jj = tid; jj < n; jj += NT) {
    const float4* r4 = (jj < wn)
        ? (const float4*)(kvs + (size_t)(ws + jj) * kD)
        : (const float4*)(kvc + (size_t)(jj - wn) * kD);
    float acc[HG];
#pragma unroll
    for (int hh = 0; hh < HG; ++hh) acc[hh] = 0.f;
#pragma unroll
    for (int u = 0; u < kD / 4; ++u) {
      const float4 b = r4[u];
#pragma unroll
      for (int hh = 0; hh < HG; ++hh) {
        const float4 a = ((const float4*)lq[hh])[u];
        acc[hh] = fmaf(a.x, b.x, acc[hh]);
        acc[hh] = fmaf(a.y, b.y, acc[hh]);
        acc[hh] = fmaf(a.z, b.z, acc[hh]);
        acc[hh] = fmaf(a.w, b.w, acc[hh]);
      }
    }
#pragma unroll
    for (int hh = 0; hh < HG; ++hh) lp[hh][jj] = acc[hh];
  }
  __syncthreads();

  // ---- softmax: wave w owns heads 2w, 2w+1 (no cross-wave deps) ----
  const int wave = tid >> 6;
  const int lane = tid & 63;
#pragma unroll
  for (int t = 0; t < 2; ++t) {
    const int hh = wave * 2 + t;
    float m = -3.0e38f;
    for (int j = lane; j < n; j += 64) m = fmaxf(m, lp[hh][j]);
#pragma unroll
    for (int off = 32; off > 0; off >>= 1) m = fmaxf(m, __shfl_xor(m, off));
    const float sk = sink[h0 + hh];
    m = fmaxf(m, sk);
    float s = 0.f;
    for (int j = lane; j < n; j += 64) {
      const float p = __expf(lp[hh][j] - m);
      lp[hh][j] = p;
      s += p;
    }
#pragma unroll
    for (int off = 32; off > 0; off >>= 1) s += __shfl_xor(s, off);
    s += __expf(sk - m);  // sink joins the denominator only
    if (lane == 0) dinv[hh] = 1.f / s;
  }
  __syncthreads();

  // ---- PV: chunk c = wave over j, lanes own float2 of D; combine in LDS ----
  const int c = wave;
  float2 acc2[HG];
#pragma unroll
  for (int hh = 0; hh < HG; ++hh) acc2[hh] = make_float2(0.f, 0.f);
  for (int j = c; j < n; j += 4) {
    const float2* r2 = (j < wn)
        ? (const float2*)(kvs + (size_t)(ws + j) * kD)
        : (const float2*)(kvc + (size_t)(j - wn) * kD);
    const float2 b = r2[lane];
#pragma unroll
    for (int hh = 0; hh < HG; ++hh) {
      const float p = lp[hh][j];
      acc2[hh].x = fmaf(p, b.x, acc2[hh].x);
      acc2[hh].y = fmaf(p, b.y, acc2[hh].y);
    }
  }
#pragma unroll
  for (int hh = 0; hh < HG; ++hh) part[c][hh][lane] = acc2[hh];
  __syncthreads();

  for (int idx = tid; idx < HG * (kD / 2); idx += NT) {
    const int hh = idx >> 6, dd = idx & 63;
    const float2 r0 = part[0][hh][dd];
    const float2 r1 = part[1][hh][dd];
    const float2 r2 = part[2][hh][dd];
    const float2 r3 = part[3][hh][dd];
    const float di = dinv[hh];
    float2 o;
    o.x = (r0.x + r1.x + r2.x + r3.x) * di;
    o.y = (r0.y + r1.y + r2.y + r3.y) * di;
    float2* orow = (float2*)(out + ((size_t)i * kH + h0 + hh) * kD);
    orow[dd] = o;
  }
}

extern "C" void kernel_launch(void* const* d_in, const int* in_sizes, int n_in,
                              void* d_out, int out_size, void* d_ws, size_t ws_size,
                              hipStream_t stream) {
  const float* q    = (const float*)d_in[0];
  const float* kvs  = (const float*)d_in[1];
  const float* sink = (const float*)d_in[2];
  const float* kvc  = (const float*)d_in[3];
  float* out = (float*)d_out;
  dim3 grid(kS, kH / HG);
  sparse_attn_f32<<<grid, NT, 0, stream>>>(q, kvs, sink, kvc, out);
}

// Round 2
// 155.742 us; speedup vs baseline: 7.2409x; 7.2409x over previous
//
#include <hip/hip_runtime.h>

// SparseAttention, MFMA bf16 flash-style.
// B=1 S=2048 H=16 D=128 WIN=512 RATIO=4; kv shared across heads.
// Per query i: window rows [i-511, i] from kv_states, compressed c with 4c+3<=i
// from kv_compress, plus per-head sink logit in the softmax denominator.
//
// Block: 8 queries x 8 heads (M=64 rows), 2 waves, each wave owns 2 m-tiles of 16.
// m-row r (0..15): q_local = r&7, h_sub = r>>3; head = h0 + mt_glob*2 + h_sub.
// Swapped MFMAs: T = K·Q^T (C: col=lane&15=m, row=kv), O^T = V^T·P (C: col=m, row=d)
// so softmax state lives at lane = m for both. kv staged fp32->bf16 per 32-row tile:
//   Ksub[buf][kv/4][d/16][4][16] (A-frags for T), KT[buf][d][kv] (A-frags for PV),
// both with XOR address-permutes for bank-uniform b128 access.

typedef __attribute__((ext_vector_type(8))) short bf16x8;
typedef __attribute__((ext_vector_type(4))) float f32x4;
typedef unsigned short u16;
typedef unsigned int u32;

constexpr int S = 2048, H = 16, D = 128, WIN = 512;
constexpr int QB = 8, HG = 8;   // M = 64
constexpr int NT = 128;         // 2 waves

__device__ __forceinline__ u16 f2bf(float f) {
  u32 u = __builtin_bit_cast(u32, f);
  return (u16)((u + 0x7FFFu + ((u >> 16) & 1u)) >> 16);
}

__global__ __launch_bounds__(NT, 2) void sparse_attn_mfma(
    const float* __restrict__ q, const float* __restrict__ kvs,
    const float* __restrict__ sink, const float* __restrict__ kvc,
    float* __restrict__ out) {

  const int it = (int)(gridDim.x - 1u - blockIdx.x);  // big-i blocks first
  const int i0 = it * QB;
  const int h0 = blockIdx.y * HG;
  const int tid = threadIdx.x;
  const int wave = tid >> 6, lane = tid & 63;
  const int lm = lane & 15, lg = lane >> 4;

  __shared__ __align__(16) u16 Ksub[2][8][8][4][16]; // 16 KB
  __shared__ __align__(16) u16 KT[2][128][40];       // 20 KB
  __shared__ __align__(16) u16 Pl[2][2][16][40];     // 5 KB

  const int iq = i0 + (lm & 7);
  const int hh0 = h0 + (wave * 2 + 0) * 2 + (lm >> 3);
  const int hh1 = h0 + (wave * 2 + 1) * 2 + (lm >> 3);

  // ---- Q fragments in registers (B-operand: col=lane&15=m, k=lg*8+j) ----
  const float qscale = 0.08838834764831845f;
  bf16x8 qf[2][4];
  {
    const float* qp0 = q + ((size_t)iq * H + hh0) * D;
    const float* qp1 = q + ((size_t)iq * H + hh1) * D;
#pragma unroll
    for (int mti = 0; mti < 2; ++mti) {
      const float* qp = mti ? qp1 : qp0;
#pragma unroll
      for (int kt = 0; kt < 4; ++kt) {
        const float4* p4 = (const float4*)(qp + kt * 32 + lg * 8);
        float4 a = p4[0], b = p4[1];
        bf16x8 v;
        v[0] = (short)f2bf(a.x * qscale); v[1] = (short)f2bf(a.y * qscale);
        v[2] = (short)f2bf(a.z * qscale); v[3] = (short)f2bf(a.w * qscale);
        v[4] = (short)f2bf(b.x * qscale); v[5] = (short)f2bf(b.y * qscale);
        v[6] = (short)f2bf(b.z * qscale); v[7] = (short)f2bf(b.w * qscale);
        qf[mti][kt] = v;
      }
    }
  }

  float skv[2] = { sink[hh0], sink[hh1] };
  float m_run[2] = { skv[0], skv[1] };
  float l_run[2] = { 0.f, 0.f };
  f32x4 oacc[2][8];
  const f32x4 fzero = {0.f, 0.f, 0.f, 0.f};
#pragma unroll
  for (int a = 0; a < 2; ++a)
#pragma unroll
    for (int b = 0; b < 8; ++b) oacc[a][b] = fzero;

  // ---- kv tiling ----
  const int w_lo = (i0 > WIN - 1) ? (i0 - (WIN - 1)) : 0;
  const int n1r = i0 + QB - w_lo;        // window rows staged
  const int n2r = (i0 + QB) >> 2;        // compressed rows staged
  const int nt1 = (n1r + 31) >> 5;
  const int nt2 = (n2r + 31) >> 5;
  const int ntiles = nt1 + nt2;

  // staging identity: thread covers kv rows r0..r0+3, d cols dc*8..dc*8+7
  const int st_t7 = tid & 7, st_r0 = st_t7 * 4, st_dc = tid >> 3;  // dc 0..15

  float4 sreg[8];

  auto sload = [&](int tt) {
    const float* src; int row0, nv;
    if (tt < nt1) { src = kvs; row0 = w_lo + tt * 32; nv = n1r - tt * 32; }
    else          { src = kvc; row0 = (tt - nt1) * 32; nv = n2r - (tt - nt1) * 32; }
    if (nv > 32) nv = 32;
    const float* p = src + (size_t)(row0 + st_r0) * D + st_dc * 8;
#pragma unroll
    for (int rr = 0; rr < 4; ++rr) {
      bool ok = (st_r0 + rr) < nv;
      const float4* p4 = (const float4*)(p + (size_t)rr * D);
      sreg[rr * 2 + 0] = ok ? p4[0] : make_float4(0.f, 0.f, 0.f, 0.f);
      sreg[rr * 2 + 1] = ok ? p4[1] : make_float4(0.f, 0.f, 0.f, 0.f);
    }
  };

  auto swrite = [&](int buf) {
    u16 bfv[4][8];
#pragma unroll
    for (int rr = 0; rr < 4; ++rr) {
      const float4& x = sreg[rr * 2];
      const float4& y = sreg[rr * 2 + 1];
      bfv[rr][0] = f2bf(x.x); bfv[rr][1] = f2bf(x.y);
      bfv[rr][2] = f2bf(x.z); bfv[rr][3] = f2bf(x.w);
      bfv[rr][4] = f2bf(y.x); bfv[rr][5] = f2bf(y.y);
      bfv[rr][6] = f2bf(y.z); bfv[rr][7] = f2bf(y.w);
    }
    // K subtiled writes: physical row = rr ^ (kvsub&3)
#pragma unroll
    for (int rr = 0; rr < 4; ++rr) {
      int rowp = rr ^ (st_t7 & 3);
      bf16x8 v;
#pragma unroll
      for (int e = 0; e < 8; ++e) v[e] = (short)bfv[rr][e];
      *(bf16x8*)&Ksub[buf][st_t7][st_dc >> 1][rowp][(st_dc & 1) * 8] = v;
    }
    // KT writes: physical d-row = (d&~7) | ((d&7) ^ ((d>>3)&7))
#pragma unroll
    for (int dd = 0; dd < 8; ++dd) {
      int dl = st_dc * 8 + dd;
      int dphys = (dl & ~7) | (dd ^ (st_dc & 7));
      uint2 w2 = make_uint2((u32)bfv[0][dd] | ((u32)bfv[1][dd] << 16),
                            (u32)bfv[2][dd] | ((u32)bfv[3][dd] << 16));
      *(uint2*)&KT[buf][dphys][st_r0] = w2;
    }
  };

  sload(0);
  swrite(0);
  __syncthreads();

  const int rrA = (lm & 3) ^ ((lm >> 2) & 3);

  for (int t = 0; t < ntiles; ++t) {
    const int cb = t & 1;
    const bool isw = t < nt1;
    const int row0 = isw ? (w_lo + t * 32) : ((t - nt1) * 32);

    if (t + 1 < ntiles) sload(t + 1);   // issue next-tile global loads early (T14)

    // ---- T = K · Q^T  (C: col = m = lm, row = kv = 4*lg + reg) ----
    f32x4 tacc[2][2];
    tacc[0][0] = fzero; tacc[0][1] = fzero; tacc[1][0] = fzero; tacc[1][1] = fzero;
#pragma unroll
    for (int kt = 0; kt < 4; ++kt) {
      const int ds = kt * 2 + (lg >> 1), co = (lg & 1) * 8;
      bf16x8 a0 = *(const bf16x8*)&Ksub[cb][(lm >> 2)][ds][rrA][co];
      bf16x8 a1 = *(const bf16x8*)&Ksub[cb][4 + (lm >> 2)][ds][rrA][co];
      tacc[0][0] = __builtin_amdgcn_mfma_f32_16x16x32_bf16(a0, qf[0][kt], tacc[0][0], 0, 0, 0);
      tacc[0][1] = __builtin_amdgcn_mfma_f32_16x16x32_bf16(a1, qf[0][kt], tacc[0][1], 0, 0, 0);
      tacc[1][0] = __builtin_amdgcn_mfma_f32_16x16x32_bf16(a0, qf[1][kt], tacc[1][0], 0, 0, 0);
      tacc[1][1] = __builtin_amdgcn_mfma_f32_16x16x32_bf16(a1, qf[1][kt], tacc[1][1], 0, 0, 0);
    }

    // ---- mask + online softmax ----
    float vv[2][8];
    float tmx[2];
#pragma unroll
    for (int mti = 0; mti < 2; ++mti) {
      float tm = -1e30f;
#pragma unroll
      for (int k2 = 0; k2 < 2; ++k2) {
#pragma unroll
        for (int r = 0; r < 4; ++r) {
          int kvl = k2 * 16 + lg * 4 + r;
          int jj = row0 + kvl;
          float x = tacc[mti][k2][r];
          bool ok = isw ? (jj <= iq && jj + WIN > iq) : (jj * 4 + 3 <= iq);
          x = ok ? x : -1e30f;
          vv[mti][k2 * 4 + r] = x;
          tm = fmaxf(tm, x);
        }
      }
      tm = fmaxf(tm, __shfl_xor(tm, 16));
      tm = fmaxf(tm, __shfl_xor(tm, 32));
      tmx[mti] = tm;
    }
    bool need = (tmx[0] > m_run[0] + 8.f) || (tmx[1] > m_run[1] + 8.f);
    if (__any(need)) {
#pragma unroll
      for (int mti = 0; mti < 2; ++mti) {
        float mn = fmaxf(m_run[mti], tmx[mti]);
        float fs = __expf(m_run[mti] - mn);
        m_run[mti] = mn;
        l_run[mti] *= fs;
#pragma unroll
        for (int dt = 0; dt < 8; ++dt) oacc[mti][dt] *= fs;
      }
    }
#pragma unroll
    for (int mti = 0; mti < 2; ++mti) {
      float s = 0.f;
#pragma unroll
      for (int k2 = 0; k2 < 2; ++k2) {
        u16 pb[4];
#pragma unroll
        for (int r = 0; r < 4; ++r) {
          float p = __expf(vv[mti][k2 * 4 + r] - m_run[mti]);
          s += p;
          pb[r] = f2bf(p);
        }
        uint2 w2 = make_uint2((u32)pb[0] | ((u32)pb[1] << 16),
                              (u32)pb[2] | ((u32)pb[3] << 16));
        *(uint2*)&Pl[wave][mti][lm][k2 * 16 + lg * 4] = w2;
      }
      l_run[mti] += s;
    }

    // ---- O^T += V^T · P  (C: col = m = lm, row = d-local = 4*lg + reg) ----
    bf16x8 pf0 = *(const bf16x8*)&Pl[wave][0][lm][lg * 8];
    bf16x8 pf1 = *(const bf16x8*)&Pl[wave][1][lm][lg * 8];
#pragma unroll
    for (int dt = 0; dt < 8; ++dt) {
      int d = dt * 16 + lm;
      int drow = (d & ~7) | ((d & 7) ^ ((d >> 3) & 7));
      bf16x8 vf = *(const bf16x8*)&KT[cb][drow][lg * 8];
      oacc[0][dt] = __builtin_amdgcn_mfma_f32_16x16x32_bf16(vf, pf0, oacc[0][dt], 0, 0, 0);
      oacc[1][dt] = __builtin_amdgcn_mfma_f32_16x16x32_bf16(vf, pf1, oacc[1][dt], 0, 0, 0);
    }

    if (t + 1 < ntiles) swrite((t + 1) & 1);  // cvt + LDS write after compute
    __syncthreads();
  }

  // ---- epilogue ----
#pragma unroll
  for (int mti = 0; mti < 2; ++mti) {
    float l = l_run[mti];
    l += __shfl_xor(l, 16);
    l += __shfl_xor(l, 32);
    l += __expf(skv[mti] - m_run[mti]);
    float di = 1.f / l;
    float* op = out + ((size_t)iq * H + (mti ? hh1 : hh0)) * D;
#pragma unroll
    for (int dt = 0; dt < 8; ++dt) {
      f32x4 o = oacc[mti][dt];
      float4 w4 = make_float4(o[0] * di, o[1] * di, o[2] * di, o[3] * di);
      *(float4*)(op + dt * 16 + lg * 4) = w4;
    }
  }
}

extern "C" void kernel_launch(void* const* d_in, const int* in_sizes, int n_in,
                              void* d_out, int out_size, void* d_ws, size_t ws_size,
                              hipStream_t stream) {
  const float* q    = (const float*)d_in[0];
  const float* kvs  = (const float*)d_in[1];
  const float* sink = (const float*)d_in[2];
  const float* kvc  = (const float*)d_in[3];
  float* out = (float*)d_out;
  dim3 grid(S / QB, H / HG);   // 256 x 2 = 512 blocks
  sparse_attn_mfma<<<grid, NT, 0, stream>>>(q, kvs, sink, kvc, out);
}

// Round 3
// 138.020 us; speedup vs baseline: 8.1707x; 1.1284x over previous
//
#include <hip/hip_runtime.h>

// SparseAttention, MFMA bf16 flash-style, split-kv in-block.
// B=1 S=2048 H=16 D=128 WIN=512 RATIO=4; kv shared across heads.
// Block: 4 queries x 8 heads (M=32 rows), 4 waves = 2 kv-splits x 2 m-tiles.
// Split s processes kv tiles {s, s+2, ...}; splits merge (m,l,O) via LDS at end.
// m-row = mtg*16 + lm: q_local = lm&3, head = h0 + mtg*4 + (lm>>2).
// Swapped MFMAs: T = K*Q^T (C col=lm=m, row=kv), O^T = V^T*P (C col=m, row=d),
// softmax state lives at lane = m for both. kv staged fp32->bf16 per 32-row tile:
// Ksub[split][kv/4][d/16][4][16] (QK A-frags), KT[split][d][kv] (PV A-frags),
// XOR-permuted rows for bank-uniform b128 access (layouts verified in R2).

typedef __attribute__((ext_vector_type(8))) short bf16x8;
typedef __attribute__((ext_vector_type(4))) float f32x4;
typedef unsigned short u16;
typedef unsigned int u32;

constexpr int S = 2048, H = 16, D = 128, WIN = 512;
constexpr int QB = 4, HG = 8;   // M = 32
constexpr int NT = 256;         // 4 waves

__device__ __forceinline__ u16 f2bf(float f) {
  u32 u = __builtin_bit_cast(u32, f);
  return (u16)((u + 0x7FFFu + ((u >> 16) & 1u)) >> 16);
}

__global__ __launch_bounds__(NT, 3) void sparse_attn_mfma2(
    const float* __restrict__ q, const float* __restrict__ kvs,
    const float* __restrict__ sink, const float* __restrict__ kvc,
    float* __restrict__ out) {

  const int it = (int)(gridDim.x - 1u - blockIdx.x);  // big-i blocks first
  const int i0 = it * QB;
  const int h0 = blockIdx.y * HG;
  const int tid = threadIdx.x;
  const int wave = tid >> 6, lane = tid & 63;
  const int split = wave >> 1, mtg = wave & 1;
  const int lm = lane & 15, lg = lane >> 4;

  // LDS: Ksub 2x8KB | KT 2x10KB | Pl 4x1.25KB = 41984 B -> 3 blocks/CU
  __shared__ __align__(16) char smem[41984];
  u16 (*Ksub)[8][4][16] = (u16(*)[8][4][16])(smem + split * 8192);
  u16 (*KTl)[40]        = (u16(*)[40])(smem + 16384 + split * 10240);
  u16 (*Pll)[40]        = (u16(*)[40])(smem + 36864 + wave * 1280);

  const int iq = i0 + (lm & 3);
  const int hh = h0 + mtg * 4 + (lm >> 2);

  // ---- Q fragments (B-operand: col=lm=m, k=lg*8+j) ----
  const float qscale = 0.08838834764831845f;  // 1/sqrt(128)
  bf16x8 qf[4];
  {
    const float* qp = q + ((size_t)iq * H + hh) * D;
#pragma unroll
    for (int kt = 0; kt < 4; ++kt) {
      const float4* p4 = (const float4*)(qp + kt * 32 + lg * 8);
      float4 a = p4[0], b = p4[1];
      bf16x8 v;
      v[0] = (short)f2bf(a.x * qscale); v[1] = (short)f2bf(a.y * qscale);
      v[2] = (short)f2bf(a.z * qscale); v[3] = (short)f2bf(a.w * qscale);
      v[4] = (short)f2bf(b.x * qscale); v[5] = (short)f2bf(b.y * qscale);
      v[6] = (short)f2bf(b.z * qscale); v[7] = (short)f2bf(b.w * qscale);
      qf[kt] = v;
    }
  }

  const float sk = sink[hh];
  float m_run = sk, l_run = 0.f;
  f32x4 oacc[8];
  const f32x4 fzero = {0.f, 0.f, 0.f, 0.f};
#pragma unroll
  for (int b = 0; b < 8; ++b) oacc[b] = fzero;

  // ---- kv tiling ----
  const int w_lo = (i0 > WIN - 1) ? (i0 - (WIN - 1)) : 0;
  const int n1r = i0 + QB - w_lo;     // window rows (<=515)
  const int n2r = (i0 + QB) >> 2;     // compressed rows
  const int nt1 = (n1r + 31) >> 5;
  const int nt2 = (n2r + 31) >> 5;
  const int ntiles = nt1 + nt2;       // >= 2 always
  const int kmax = (ntiles + 1) >> 1;

  // staging: each split's 128 threads cover 32 rows x 128 cols
  const int st = tid & 127;
  const int st_t7 = st & 7, st_r0 = st_t7 * 4, st_dc = st >> 3;  // dc 0..15

  float4 sreg[8];
  auto sload = [&](int tt) {
    const float* src; int row0, nv;
    if (tt < nt1) { src = kvs; row0 = w_lo + tt * 32; nv = n1r - tt * 32; }
    else          { src = kvc; row0 = (tt - nt1) * 32; nv = n2r - (tt - nt1) * 32; }
    if (nv > 32) nv = 32;
    const float* p = src + (size_t)(row0 + st_r0) * D + st_dc * 8;
#pragma unroll
    for (int rr = 0; rr < 4; ++rr) {
      bool ok = (st_r0 + rr) < nv;
      const float4* p4 = (const float4*)(p + (size_t)rr * D);
      sreg[rr * 2 + 0] = ok ? p4[0] : make_float4(0.f, 0.f, 0.f, 0.f);
      sreg[rr * 2 + 1] = ok ? p4[1] : make_float4(0.f, 0.f, 0.f, 0.f);
    }
  };

  auto swrite = [&]() {
    u16 bfv[4][8];
#pragma unroll
    for (int rr = 0; rr < 4; ++rr) {
      const float4& x = sreg[rr * 2];
      const float4& y = sreg[rr * 2 + 1];
      bfv[rr][0] = f2bf(x.x); bfv[rr][1] = f2bf(x.y);
      bfv[rr][2] = f2bf(x.z); bfv[rr][3] = f2bf(x.w);
      bfv[rr][4] = f2bf(y.x); bfv[rr][5] = f2bf(y.y);
      bfv[rr][6] = f2bf(y.z); bfv[rr][7] = f2bf(y.w);
    }
#pragma unroll
    for (int rr = 0; rr < 4; ++rr) {   // K subtiled, row-XOR
      int rowp = rr ^ (st_t7 & 3);
      bf16x8 v;
#pragma unroll
      for (int e = 0; e < 8; ++e) v[e] = (short)bfv[rr][e];
      *(bf16x8*)&Ksub[st_t7][st_dc >> 1][rowp][(st_dc & 1) * 8] = v;
    }
#pragma unroll
    for (int dd = 0; dd < 8; ++dd) {   // KT (V^T), d-XOR
      int dl = st_dc * 8 + dd;
      int dphys = (dl & ~7) | (dd ^ (st_dc & 7));
      uint2 w2 = make_uint2((u32)bfv[0][dd] | ((u32)bfv[1][dd] << 16),
                            (u32)bfv[2][dd] | ((u32)bfv[3][dd] << 16));
      *(uint2*)&KTl[dphys][st_r0] = w2;
    }
  };

  sload(split);  // prologue: split s starts at tile s

  const int rrA = (lm & 3) ^ ((lm >> 2) & 3);

  for (int k = 0; k < kmax; ++k) {
    const int tt = 2 * k + split;
    const bool active = tt < ntiles;     // wave-uniform
    __syncthreads();                     // buffer free (prev tile consumed)
    if (active) swrite();
    __syncthreads();                     // staged data visible
    const int tn = tt + 2;
    if (tn < ntiles) sload(tn);          // prefetch next tile (overlaps compute)
    if (!active) continue;               // barrier counts stay matched

    const bool isw = tt < nt1;
    const int row0 = isw ? (w_lo + tt * 32) : ((tt - nt1) * 32);

    // ---- T = K·Q^T ----
    f32x4 tacc[2];
    tacc[0] = fzero; tacc[1] = fzero;
#pragma unroll
    for (int kt = 0; kt < 4; ++kt) {
      const int ds = kt * 2 + (lg >> 1), co = (lg & 1) * 8;
      bf16x8 a0 = *(const bf16x8*)&Ksub[(lm >> 2)][ds][rrA][co];
      bf16x8 a1 = *(const bf16x8*)&Ksub[4 + (lm >> 2)][ds][rrA][co];
      tacc[0] = __builtin_amdgcn_mfma_f32_16x16x32_bf16(a0, qf[kt], tacc[0], 0, 0, 0);
      tacc[1] = __builtin_amdgcn_mfma_f32_16x16x32_bf16(a1, qf[kt], tacc[1], 0, 0, 0);
    }

    // ---- mask + online softmax (state at lane = m) ----
    float vv[8];
    float tm = -1e30f;
#pragma unroll
    for (int k2 = 0; k2 < 2; ++k2) {
#pragma unroll
      for (int r = 0; r < 4; ++r) {
        int jj = row0 + k2 * 16 + lg * 4 + r;
        float x = tacc[k2][r];
        bool ok = isw ? (jj <= iq && jj + WIN > iq) : (jj * 4 + 3 <= iq);
        x = ok ? x : -1e30f;
        vv[k2 * 4 + r] = x;
        tm = fmaxf(tm, x);
      }
    }
    tm = fmaxf(tm, __shfl_xor(tm, 16));
    tm = fmaxf(tm, __shfl_xor(tm, 32));
    if (__any(tm > m_run + 8.f)) {       // defer-max (T13)
      float mn = fmaxf(m_run, tm);
      float fs = __expf(m_run - mn);
      m_run = mn; l_run *= fs;
#pragma unroll
      for (int dt = 0; dt < 8; ++dt) oacc[dt] *= fs;
    }
    float s = 0.f;
#pragma unroll
    for (int k2 = 0; k2 < 2; ++k2) {
      u16 pb[4];
#pragma unroll
      for (int r = 0; r < 4; ++r) {
        float p = __expf(vv[k2 * 4 + r] - m_run);
        s += p; pb[r] = f2bf(p);
      }
      *(uint2*)&Pll[lm][k2 * 16 + lg * 4] =
          make_uint2((u32)pb[0] | ((u32)pb[1] << 16),
                     (u32)pb[2] | ((u32)pb[3] << 16));
    }
    l_run += s;

    // ---- O^T += V^T·P ----
    bf16x8 pf = *(const bf16x8*)&Pll[lm][lg * 8];
#pragma unroll
    for (int dt = 0; dt < 8; ++dt) {
      int d = dt * 16 + lm;
      int drow = (d & ~7) | ((d & 7) ^ ((d >> 3) & 7));
      bf16x8 vf = *(const bf16x8*)&KTl[drow][lg * 8];
      oacc[dt] = __builtin_amdgcn_mfma_f32_16x16x32_bf16(vf, pf, oacc[dt], 0, 0, 0);
    }
  }

  // ---- split merge (overlay on staging region; staging is dead now) ----
  float l = l_run;
  l += __shfl_xor(l, 16);
  l += __shfl_xor(l, 32);

  float (*Ocomb)[16][128] = (float(*)[16][128])(smem);   // 16 KB
  float* Mcomb = (float*)(smem + 16384);
  float* Lcomb = (float*)(smem + 16384 + 128);

  __syncthreads();   // all compute done before overlay writes
  if (split == 1) {
#pragma unroll
    for (int dt = 0; dt < 8; ++dt)
      *(f32x4*)&Ocomb[mtg][lm][dt * 16 + lg * 4] = oacc[dt];
    if (lg == 0) { Mcomb[mtg * 16 + lm] = m_run; Lcomb[mtg * 16 + lm] = l; }
  }
  __syncthreads();
  if (split == 0) {
    float m1 = Mcomb[mtg * 16 + lm], l1 = Lcomb[mtg * 16 + lm];
    float mf = fmaxf(m_run, m1);
    float a0 = __expf(m_run - mf), a1 = __expf(m1 - mf);
    float lf = l * a0 + l1 * a1 + __expf(sk - mf);  // sink joins denom once
    float di = 1.f / lf;
    float* op = out + ((size_t)iq * H + hh) * D;
#pragma unroll
    for (int dt = 0; dt < 8; ++dt) {
      f32x4 o1 = *(f32x4*)&Ocomb[mtg][lm][dt * 16 + lg * 4];
      float4 w4 = make_float4((oacc[dt][0] * a0 + o1[0] * a1) * di,
                              (oacc[dt][1] * a0 + o1[1] * a1) * di,
                              (oacc[dt][2] * a0 + o1[2] * a1) * di,
                              (oacc[dt][3] * a0 + o1[3] * a1) * di);
      *(float4*)(op + dt * 16 + lg * 4) = w4;
    }
  }
}

extern "C" void kernel_launch(void* const* d_in, const int* in_sizes, int n_in,
                              void* d_out, int out_size, void* d_ws, size_t ws_size,
                              hipStream_t stream) {
  const float* q    = (const float*)d_in[0];
  const float* kvs  = (const float*)d_in[1];
  const float* sink = (const float*)d_in[2];
  const float* kvc  = (const float*)d_in[3];
  float* out = (float*)d_out;
  dim3 grid(S / QB, H / HG);   // 512 x 2 = 1024 blocks
  sparse_attn_mfma2<<<grid, NT, 0, stream>>>(q, kvs, sink, kvc, out);
}

// Round 5
// 117.142 us; speedup vs baseline: 9.6269x; 1.1782x over previous
//
#include <hip/hip_runtime.h>

// SparseAttention, MFMA bf16 flash-style, split-kv in-block, pre-converted kv.
// B=1 S=2048 H=16 D=128 WIN=512 RATIO=4; kv shared across heads.
// Kernel A: convert concat(kv_states, kv_compress) -> bf16 in d_ws,
//           2592 rows x 128 (rows 2560..2591 zero pad).
// Kernel B: block = 4 queries x 8 heads (M=32), 4 waves = 2 kv-splits x 2 m-tiles.
// Split s processes kv tiles {s, s+2, ...}; splits merge (m,l,O) via LDS at end.
// Swapped MFMAs: T = K*Q^T (C col=lm=m, row=kv), O^T = V^T*P (C col=m, row=d).
// kv staged bf16 per 32-row tile: Ksub[kv/4][d/16][4][16] (QK A-frags, row-XOR),
// KT[d][kv] (PV A-frags, d-XOR). Layouts verified R2/R3.

typedef __attribute__((ext_vector_type(8))) short bf16x8;
typedef __attribute__((ext_vector_type(4))) float f32x4;
typedef unsigned short u16;
typedef unsigned int u32;

constexpr int S = 2048, H = 16, D = 128, WIN = 512;
constexpr int QB = 4, HG = 8;   // M = 32
constexpr int NT = 256;         // 4 waves
constexpr int KVROWS = 2592;    // 2048 window + 512 compressed + 32 zero pad

__device__ __forceinline__ u16 f2bf(float f) {
  u32 u = __builtin_bit_cast(u32, f);
  return (u16)((u + 0x7FFFu + ((u >> 16) & 1u)) >> 16);
}

// ---- Kernel A: kv fp32 -> bf16 concat+pad into ws ----
__global__ __launch_bounds__(256) void precvt_kv(
    const float* __restrict__ kvs, const float* __restrict__ kvc,
    u16* __restrict__ dst) {
  int idx = blockIdx.x * 256 + threadIdx.x;      // one per 8 elements
  if (idx >= KVROWS * (D / 8)) return;
  int row = idx >> 4, c8 = (idx & 15) * 8;
  float4 a = make_float4(0.f, 0.f, 0.f, 0.f), b = a;
  if (row < 2048) {
    const float4* p = (const float4*)(kvs + (size_t)row * D + c8);
    a = p[0]; b = p[1];
  } else if (row < 2560) {
    const float4* p = (const float4*)(kvc + (size_t)(row - 2048) * D + c8);
    a = p[0]; b = p[1];
  }
  bf16x8 v;
  v[0] = (short)f2bf(a.x); v[1] = (short)f2bf(a.y);
  v[2] = (short)f2bf(a.z); v[3] = (short)f2bf(a.w);
  v[4] = (short)f2bf(b.x); v[5] = (short)f2bf(b.y);
  v[6] = (short)f2bf(b.z); v[7] = (short)f2bf(b.w);
  *(bf16x8*)(dst + (size_t)row * D + c8) = v;
}

// ---- Kernel B: attention ----
__global__ __launch_bounds__(NT, 3) void sparse_attn_mfma3(
    const float* __restrict__ q, const u16* __restrict__ kvb,
    const float* __restrict__ sink, float* __restrict__ out) {

  const int it = (int)(gridDim.x - 1u - blockIdx.x);  // big-i blocks first
  const int i0 = it * QB;
  const int h0 = blockIdx.y * HG;
  const int tid = threadIdx.x;
  const int wave = tid >> 6, lane = tid & 63;
  const int split = wave >> 1, mtg = wave & 1;
  const int lm = lane & 15, lg = lane >> 4;

  // LDS: Ksub 2x8KB | KT 2x10KB | Pl 4x1.25KB = 41984 B -> 3 blocks/CU
  __shared__ __align__(16) char smem[41984];
  u16 (*Ksub)[8][4][16] = (u16(*)[8][4][16])(smem + split * 8192);
  u16 (*KTl)[40]        = (u16(*)[40])(smem + 16384 + split * 10240);
  u16 (*Pll)[40]        = (u16(*)[40])(smem + 36864 + wave * 1280);

  const int iq = i0 + (lm & 3);
  const int hh = h0 + mtg * 4 + (lm >> 2);

  // ---- Q fragments (B-operand: col=lm=m, k=lg*8+j) ----
  const float qscale = 0.08838834764831845f;  // 1/sqrt(128)
  bf16x8 qf[4];
  {
    const float* qp = q + ((size_t)iq * H + hh) * D;
#pragma unroll
    for (int kt = 0; kt < 4; ++kt) {
      const float4* p4 = (const float4*)(qp + kt * 32 + lg * 8);
      float4 a = p4[0], b = p4[1];
      bf16x8 v;
      v[0] = (short)f2bf(a.x * qscale); v[1] = (short)f2bf(a.y * qscale);
      v[2] = (short)f2bf(a.z * qscale); v[3] = (short)f2bf(a.w * qscale);
      v[4] = (short)f2bf(b.x * qscale); v[5] = (short)f2bf(b.y * qscale);
      v[6] = (short)f2bf(b.z * qscale); v[7] = (short)f2bf(b.w * qscale);
      qf[kt] = v;
    }
  }

  const float sk = sink[hh];
  float m_run = sk, l_run = 0.f;
  f32x4 oacc[8];
  const f32x4 fzero = {0.f, 0.f, 0.f, 0.f};
#pragma unroll
  for (int b = 0; b < 8; ++b) oacc[b] = fzero;

  // ---- kv tiling ----
  const int w_lo = (i0 > WIN - 1) ? (i0 - (WIN - 1)) : 0;
  const int n1r = i0 + QB - w_lo;     // window rows (<=515)
  const int n2r = (i0 + QB) >> 2;     // compressed rows
  const int nt1 = (n1r + 31) >> 5;
  const int nt2 = (n2r + 31) >> 5;
  const int ntiles = nt1 + nt2;       // >= 2 always
  const int kmax = (ntiles + 1) >> 1;

  // staging: each split's 128 threads cover 32 rows x 128 cols
  const int st = tid & 127;
  const int st_t7 = st & 7, st_r0 = st_t7 * 4, st_dc = st >> 3;  // dc 0..15

  uint4 sreg[4];   // 4 rows x 8 bf16
  auto sload = [&](int tt) {
    const int row0 = (tt < nt1) ? (w_lo + tt * 32) : (2048 + (tt - nt1) * 32);
    const u16* p = kvb + (size_t)(row0 + st_r0) * D + st_dc * 8;
#pragma unroll
    for (int rr = 0; rr < 4; ++rr)
      sreg[rr] = *(const uint4*)(p + (size_t)rr * D);
  };

  auto swrite = [&]() {
#pragma unroll
    for (int rr = 0; rr < 4; ++rr) {   // K subtiled, row-XOR
      int rowp = rr ^ (st_t7 & 3);
      *(uint4*)&Ksub[st_t7][st_dc >> 1][rowp][(st_dc & 1) * 8] = sreg[rr];
    }
    const u32* R0 = (const u32*)&sreg[0];
    const u32* R1 = (const u32*)&sreg[1];
    const u32* R2 = (const u32*)&sreg[2];
    const u32* R3 = (const u32*)&sreg[3];
#pragma unroll
    for (int dd2 = 0; dd2 < 4; ++dd2) {   // KT (V^T), d-XOR, v_perm repack
#pragma unroll
      for (int h = 0; h < 2; ++h) {
        const u32 sel = h ? 0x07060302u : 0x05040100u;
        u32 lo = __builtin_amdgcn_perm(R1[dd2], R0[dd2], sel);
        u32 hi = __builtin_amdgcn_perm(R3[dd2], R2[dd2], sel);
        int dl = st_dc * 8 + dd2 * 2 + h;
        int dphys = (dl & ~7) | ((dl & 7) ^ (st_dc & 7));
        *(uint2*)&KTl[dphys][st_r0] = make_uint2(lo, hi);
      }
    }
  };

  sload(split);  // prologue: split s starts at tile s

  const int rrA = (lm & 3) ^ ((lm >> 2) & 3);

  for (int k = 0; k < kmax; ++k) {
    const int tt = 2 * k + split;
    const bool active = tt < ntiles;     // wave-uniform
    __syncthreads();                     // buffer free (prev tile consumed)
    if (active) swrite();
    __syncthreads();                     // staged data visible
    const int tn = tt + 2;
    if (tn < ntiles) sload(tn);          // prefetch next tile (overlaps compute)
    if (!active) continue;               // barrier counts stay matched

    const bool isw = tt < nt1;
    const int row0 = isw ? (w_lo + tt * 32) : ((tt - nt1) * 32);  // mask-space row

    // ---- T = K·Q^T ----
    f32x4 tacc[2];
    tacc[0] = fzero; tacc[1] = fzero;
    __builtin_amdgcn_s_setprio(1);
#pragma unroll
    for (int kt = 0; kt < 4; ++kt) {
      const int ds = kt * 2 + (lg >> 1), co = (lg & 1) * 8;
      bf16x8 a0 = *(const bf16x8*)&Ksub[(lm >> 2)][ds][rrA][co];
      bf16x8 a1 = *(const bf16x8*)&Ksub[4 + (lm >> 2)][ds][rrA][co];
      tacc[0] = __builtin_amdgcn_mfma_f32_16x16x32_bf16(a0, qf[kt], tacc[0], 0, 0, 0);
      tacc[1] = __builtin_amdgcn_mfma_f32_16x16x32_bf16(a1, qf[kt], tacc[1], 0, 0, 0);
    }
    __builtin_amdgcn_s_setprio(0);

    // ---- mask (wave-uniform fast path) + online softmax (state at lane=m) ----
    float vv[8];
    float tm = -1e30f;
    const bool fullv = isw ? (row0 >= i0 + 3 - (WIN - 1)) && (row0 + 31 <= i0)
                           : ((row0 + 31) * 4 + 3 <= i0);
    if (fullv) {
#pragma unroll
      for (int k2 = 0; k2 < 2; ++k2)
#pragma unroll
        for (int r = 0; r < 4; ++r) {
          float x = tacc[k2][r];
          vv[k2 * 4 + r] = x;
          tm = fmaxf(tm, x);
        }
    } else {
#pragma unroll
      for (int k2 = 0; k2 < 2; ++k2)
#pragma unroll
        for (int r = 0; r < 4; ++r) {
          int jj = row0 + k2 * 16 + lg * 4 + r;
          float x = tacc[k2][r];
          bool ok = isw ? (jj <= iq && jj + WIN > iq) : (jj * 4 + 3 <= iq);
          x = ok ? x : -1e30f;
          vv[k2 * 4 + r] = x;
          tm = fmaxf(tm, x);
        }
    }
    tm = fmaxf(tm, __shfl_xor(tm, 16));
    tm = fmaxf(tm, __shfl_xor(tm, 32));
    if (__any(tm > m_run + 8.f)) {       // defer-max (T13)
      float mn = fmaxf(m_run, tm);
      float fs = __expf(m_run - mn);
      m_run = mn; l_run *= fs;
#pragma unroll
      for (int dt = 0; dt < 8; ++dt) oacc[dt] *= fs;
    }
    float s = 0.f;
#pragma unroll
    for (int k2 = 0; k2 < 2; ++k2) {
      u16 pb[4];
#pragma unroll
      for (int r = 0; r < 4; ++r) {
        float p = __expf(vv[k2 * 4 + r] - m_run);
        s += p; pb[r] = f2bf(p);
      }
      *(uint2*)&Pll[lm][k2 * 16 + lg * 4] =
          make_uint2((u32)pb[0] | ((u32)pb[1] << 16),
                     (u32)pb[2] | ((u32)pb[3] << 16));
    }
    l_run += s;

    // ---- O^T += V^T·P ----
    bf16x8 pf = *(const bf16x8*)&Pll[lm][lg * 8];
    __builtin_amdgcn_s_setprio(1);
#pragma unroll
    for (int dt = 0; dt < 8; ++dt) {
      int d = dt * 16 + lm;
      int drow = (d & ~7) | ((d & 7) ^ ((d >> 3) & 7));
      bf16x8 vf = *(const bf16x8*)&KTl[drow][lg * 8];
      oacc[dt] = __builtin_amdgcn_mfma_f32_16x16x32_bf16(vf, pf, oacc[dt], 0, 0, 0);
    }
    __builtin_amdgcn_s_setprio(0);
  }

  // ---- split merge (overlay on staging region; staging is dead now) ----
  float l = l_run;
  l += __shfl_xor(l, 16);
  l += __shfl_xor(l, 32);

  float (*Ocomb)[16][128] = (float(*)[16][128])(smem);   // 16 KB
  float* Mcomb = (float*)(smem + 16384);
  float* Lcomb = (float*)(smem + 16384 + 128);

  __syncthreads();   // all compute done before overlay writes
  if (split == 1) {
#pragma unroll
    for (int dt = 0; dt < 8; ++dt)
      *(f32x4*)&Ocomb[mtg][lm][dt * 16 + lg * 4] = oacc[dt];
    if (lg == 0) { Mcomb[mtg * 16 + lm] = m_run; Lcomb[mtg * 16 + lm] = l; }
  }
  __syncthreads();
  if (split == 0) {
    float m1 = Mcomb[mtg * 16 + lm], l1 = Lcomb[mtg * 16 + lm];
    float mf = fmaxf(m_run, m1);
    float a0 = __expf(m_run - mf), a1 = __expf(m1 - mf);
    float lf = l * a0 + l1 * a1 + __expf(sk - mf);  // sink joins denom once
    float di = 1.f / lf;
    float* op = out + ((size_t)iq * H + hh) * D;
#pragma unroll
    for (int dt = 0; dt < 8; ++dt) {
      f32x4 o1 = *(f32x4*)&Ocomb[mtg][lm][dt * 16 + lg * 4];
      float4 w4 = make_float4((oacc[dt][0] * a0 + o1[0] * a1) * di,
                              (oacc[dt][1] * a0 + o1[1] * a1) * di,
                              (oacc[dt][2] * a0 + o1[2] * a1) * di,
                              (oacc[dt][3] * a0 + o1[3] * a1) * di);
      *(float4*)(op + dt * 16 + lg * 4) = w4;
    }
  }
}

extern "C" void kernel_launch(void* const* d_in, const int* in_sizes, int n_in,
                              void* d_out, int out_size, void* d_ws, size_t ws_size,
                              hipStream_t stream) {
  const float* q    = (const float*)d_in[0];
  const float* kvs  = (const float*)d_in[1];
  const float* sink = (const float*)d_in[2];
  const float* kvc  = (const float*)d_in[3];
  float* out = (float*)d_out;
  u16* kvb = (u16*)d_ws;   // 2592*128*2 = 663,552 B

  {
    int nthr = KVROWS * (D / 8);
    precvt_kv<<<(nthr + 255) / 256, 256, 0, stream>>>(kvs, kvc, kvb);
  }
  dim3 grid(S / QB, H / HG);   // 512 x 2 = 1024 blocks
  sparse_attn_mfma3<<<grid, NT, 0, stream>>>(q, kvb, sink, out);
}